// Round 13
// baseline (1416.248 us; speedup 1.0000x reference)
//
#include <hip/hip_runtime.h>
#include <hip/hip_bf16.h>

// GPT forward: V=32000 D=1024 S=1024 L=4 H=16 DK=DV=64 B=4 DFF=4096
#define V_   32000
#define VP_  32768     // padded lmwt allocation (rows >= 32000 unused)
#define D_   1024
#define S_   1024
#define L_   4
#define H_   16
#define B_   4
#define DFF_ 4096
#define M_   (B_*S_)   // 4096 token rows

using bf_t = __hip_bfloat16;
typedef __bf16 bf16x8 __attribute__((ext_vector_type(8)));
typedef __bf16 bf16x4 __attribute__((ext_vector_type(4)));
typedef float  f32x4  __attribute__((ext_vector_type(4)));

#define AS1(p) ((__attribute__((address_space(1))) void*)(p))
#define AS3(p) ((__attribute__((address_space(3))) void*)(p))

// ---------------------------------------------------------------------------
// Transpose f32 [R,C] -> bf16 [C,R], batched over two strides (z = z1*n2+z2)
// ---------------------------------------------------------------------------
__global__ __launch_bounds__(256) void k_transpose_bf16(
    const float* __restrict__ src, bf_t* __restrict__ dst,
    int R, int C, long srcS1, long srcS2, long dstS1, long dstS2, int n2)
{
  const int z  = blockIdx.z;
  const int z1 = z / n2, z2 = z % n2;
  src += (size_t)z1 * srcS1 + (size_t)z2 * srcS2;
  dst += (size_t)z1 * dstS1 + (size_t)z2 * dstS2;
  __shared__ float tile[32][33];
  const int c0 = blockIdx.x * 32, r0 = blockIdx.y * 32;
  const int lx = threadIdx.x, ly = threadIdx.y;  // 32 x 8
  #pragma unroll
  for (int i = 0; i < 32; i += 8)
    tile[ly + i][lx] = src[(size_t)(r0 + ly + i) * C + (c0 + lx)];
  __syncthreads();
  #pragma unroll
  for (int i = 0; i < 32; i += 8)
    dst[(size_t)(c0 + ly + i) * R + (r0 + lx)] = __float2bfloat16(tile[lx][ly + i]);
}

// ---------------------------------------------------------------------------
// Embedding: x[b,s,:] = tok_emb[idx[b,s],:] + pos_emb[s,:]
// ---------------------------------------------------------------------------
__global__ __launch_bounds__(256) void k_embed(
    const int* __restrict__ idx, const float* __restrict__ tok,
    const float* __restrict__ pos, float* __restrict__ x)
{
  const int row = blockIdx.x;          // b*S + s
  const int s   = row & (S_ - 1);
  const int t   = idx[row];
  const float4* tr = (const float4*)(tok + (size_t)t * D_);
  const float4* pr = (const float4*)(pos + (size_t)s * D_);
  float4* xr = (float4*)(x + (size_t)row * D_);
  const int i = threadIdx.x;
  float4 a = tr[i], b = pr[i];
  xr[i] = make_float4(a.x + b.x, a.y + b.y, a.z + b.z, a.w + b.w);
}

// ---------------------------------------------------------------------------
// LayerNorm (f32 in) -> bf16 out.  One block (256 thr) per row, D=1024.
// ---------------------------------------------------------------------------
__global__ __launch_bounds__(256) void k_ln(
    const float* __restrict__ x, const float* __restrict__ g,
    const float* __restrict__ bb, bf_t* __restrict__ out)
{
  __shared__ float red[8];
  const int row = blockIdx.x, tid = threadIdx.x;
  const float4 v = ((const float4*)(x + (size_t)row * D_))[tid];
  float s = v.x + v.y + v.z + v.w;
  #pragma unroll
  for (int o = 32; o > 0; o >>= 1) s += __shfl_down(s, o);
  if ((tid & 63) == 0) red[tid >> 6] = s;
  __syncthreads();
  const float mu = (red[0] + red[1] + red[2] + red[3]) * (1.f / D_);
  const float dx = v.x - mu, dy = v.y - mu, dz = v.z - mu, dw = v.w - mu;
  float ss = dx*dx + dy*dy + dz*dz + dw*dw;
  #pragma unroll
  for (int o = 32; o > 0; o >>= 1) ss += __shfl_down(ss, o);
  if ((tid & 63) == 0) red[4 + (tid >> 6)] = ss;
  __syncthreads();
  const float var = (red[4] + red[5] + red[6] + red[7]) * (1.f / D_);
  const float rs  = rsqrtf(var + 1e-5f);
  const float4 gv = ((const float4*)g)[tid];
  const float4 bv = ((const float4*)bb)[tid];
  const size_t base = (size_t)row * D_ + tid * 4;
  out[base + 0] = __float2bfloat16(dx * rs * gv.x + bv.x);
  out[base + 1] = __float2bfloat16(dy * rs * gv.y + bv.y);
  out[base + 2] = __float2bfloat16(dz * rs * gv.z + bv.z);
  out[base + 3] = __float2bfloat16(dw * rs * gv.w + bv.w);
}

// ---------------------------------------------------------------------------
// Fused split-K combine + LayerNorm:
//   x[row] += P0[row] + P1[row] (+ cbias);  out[row] = LN(x[row]) (bf16)
// ---------------------------------------------------------------------------
__global__ __launch_bounds__(256) void k_combine_ln(
    float* __restrict__ x, const float* __restrict__ P, long pstride,
    const float* __restrict__ cbias,
    const float* __restrict__ g, const float* __restrict__ bb,
    bf_t* __restrict__ out)
{
  __shared__ float red[8];
  const int row = blockIdx.x, tid = threadIdx.x;
  const size_t i = (size_t)row * 256 + tid;
  float4 a = ((const float4*)x)[i];
  {
    const float4 p0 = ((const float4*)P)[i];
    const float4 p1 = ((const float4*)(P + pstride))[i];
    a.x += p0.x + p1.x; a.y += p0.y + p1.y;
    a.z += p0.z + p1.z; a.w += p0.w + p1.w;
  }
  if (cbias) {
    const float4 bv = ((const float4*)cbias)[tid];
    a.x += bv.x; a.y += bv.y; a.z += bv.z; a.w += bv.w;
  }
  ((float4*)x)[i] = a;
  float s = a.x + a.y + a.z + a.w;
  #pragma unroll
  for (int o = 32; o > 0; o >>= 1) s += __shfl_down(s, o);
  if ((tid & 63) == 0) red[tid >> 6] = s;
  __syncthreads();
  const float mu = (red[0] + red[1] + red[2] + red[3]) * (1.f / D_);
  const float dx = a.x - mu, dy = a.y - mu, dz = a.z - mu, dw = a.w - mu;
  float ss = dx*dx + dy*dy + dz*dz + dw*dw;
  #pragma unroll
  for (int o = 32; o > 0; o >>= 1) ss += __shfl_down(ss, o);
  if ((tid & 63) == 0) red[4 + (tid >> 6)] = ss;
  __syncthreads();
  const float var = (red[4] + red[5] + red[6] + red[7]) * (1.f / D_);
  const float rs  = rsqrtf(var + 1e-5f);
  const float4 gv = ((const float4*)g)[tid];
  const float4 bv = ((const float4*)bb)[tid];
  const size_t base = (size_t)row * D_ + tid * 4;
  out[base + 0] = __float2bfloat16(dx * rs * gv.x + bv.x);
  out[base + 1] = __float2bfloat16(dy * rs * gv.y + bv.y);
  out[base + 2] = __float2bfloat16(dz * rs * gv.z + bv.z);
  out[base + 3] = __float2bfloat16(dw * rs * gv.w + bv.w);
}

// ---------------------------------------------------------------------------
// 128x128 GEMM (PARTS=1 direct, or split-K partials).  2-3 blocks/CU
// (64KB LDS, ~150 total regs) -> cross-block barrier overlap.
// Double-buffered LDS + 1-tile-deep prefetch + XOR swizzle.
// ROUND-13: now also used for QKV (768 blocks) and FFN1 (1024 blocks) —
// replacing the 1-block/CU 256² pipeline at those shapes.
// Mapping needs nN % 8 == 0 (24/32/8 here) and nM = 32.
// ---------------------------------------------------------------------------
template<bool HAS_BIAS, bool RELU, bool OUT_BF16, bool NT, int PARTS>
__global__ __launch_bounds__(256) void k_gemm(
    const bf_t* __restrict__ A, const bf_t* __restrict__ Bt,
    float* outF, bf_t* outB,
    const float* __restrict__ bias,
    int N, int ld, int Klen, long pstride)
{
  __shared__ __bf16 As[2][128 * 64];
  __shared__ __bf16 Bs[2][128 * 64];
  const int tid  = threadIdx.x;
  const int lane = tid & 63, wid = tid >> 6;
  int bp = blockIdx.x, kh = 0;
  if (PARTS > 1) { const int T = gridDim.x / PARTS; kh = bp / T; bp %= T; }
  const int i  = bp >> 3;
  const int nt = (bp & 7) + 8 * (i >> 5);
  const int mt = i & 31;
  const int m0 = mt * 128;
  const int n0 = nt * 128;
  if (n0 >= N) return;
  const int kb = kh * Klen;
  f32x4 acc[4][4] = {};

  const int srow = lane >> 3;
  const int scol = ((lane & 7) ^ (lane >> 3)) * 8;
  const int mw = (wid >> 1) * 64, nw = (wid & 1) * 64;
  const int NTk = Klen >> 6;

  #pragma unroll
  for (int i2 = 0; i2 < 4; ++i2) {
    const int chunk = i2 * 4 + wid;
    const int r = chunk * 8 + srow;
    __builtin_amdgcn_global_load_lds(AS1(A  + (size_t)(m0 + r) * ld + kb + scol),
                                     AS3(&As[0][chunk * 512]), 16, 0, 0);
    __builtin_amdgcn_global_load_lds(AS1(Bt + (size_t)(n0 + r) * ld + kb + scol),
                                     AS3(&Bs[0][chunk * 512]), 16, 0, 0);
  }

  for (int t = 0; t < NTk; ++t) {
    __syncthreads();   // implicit vmcnt(0): stage(t) landed for ALL waves
    if (t + 1 < NTk) {
      const int kt = (t + 1) << 6;
      #pragma unroll
      for (int i2 = 0; i2 < 4; ++i2) {
        const int chunk = i2 * 4 + wid;
        const int r = chunk * 8 + srow;
        __builtin_amdgcn_global_load_lds(AS1(A  + (size_t)(m0 + r) * ld + kb + kt + scol),
                                         AS3(&As[(t + 1) & 1][chunk * 512]), 16, 0, 0);
        __builtin_amdgcn_global_load_lds(AS1(Bt + (size_t)(n0 + r) * ld + kb + kt + scol),
                                         AS3(&Bs[(t + 1) & 1][chunk * 512]), 16, 0, 0);
      }
    }
    const __bf16* Ab = As[t & 1];
    const __bf16* Bb = Bs[t & 1];
    #pragma unroll
    for (int kk = 0; kk < 2; ++kk) {
      const int ck = kk * 4 + (lane >> 4);
      bf16x8 af[4], bfr[4];
      #pragma unroll
      for (int mi = 0; mi < 4; ++mi) {
        const int r = mw + mi * 16 + (lane & 15);
        af[mi] = *(const bf16x8*)&Ab[r * 64 + ((ck ^ (r & 7)) * 8)];
      }
      #pragma unroll
      for (int ni = 0; ni < 4; ++ni) {
        const int r = nw + ni * 16 + (lane & 15);
        bfr[ni] = *(const bf16x8*)&Bb[r * 64 + ((ck ^ (r & 7)) * 8)];
      }
      #pragma unroll
      for (int mi = 0; mi < 4; ++mi)
        #pragma unroll
        for (int ni = 0; ni < 4; ++ni)
          acc[mi][ni] = __builtin_amdgcn_mfma_f32_16x16x32_bf16(af[mi], bfr[ni], acc[mi][ni], 0, 0, 0);
    }
  }

  float* outP = outF + (PARTS > 1 ? (size_t)kh * pstride : 0);
  const int cr = (lane >> 4) * 4, cc = lane & 15;
  #pragma unroll
  for (int mi = 0; mi < 4; ++mi) {
    #pragma unroll
    for (int ni = 0; ni < 4; ++ni) {
      const int col = n0 + nw + ni * 16 + cc;
      const float bv = HAS_BIAS ? bias[col] : 0.f;
      #pragma unroll
      for (int j = 0; j < 4; ++j) {
        const int row = m0 + mw + mi * 16 + cr + j;
        float v = acc[mi][ni][j] + bv;
        if (RELU)  v = fmaxf(v, 0.f);
        if (OUT_BF16) {
          outB[(size_t)row * N + col] = __float2bfloat16(v);
        } else if (NT) {
          __builtin_nontemporal_store(v, &outP[(size_t)row * N + col]);
        } else {
          outP[(size_t)row * N + col] = v;
        }
      }
    }
  }
}

// ---------------------------------------------------------------------------
// 256x256 8-PHASE deep-pipelined GEMM (T2+T3+T4+T5), C = A[M,K]*Bt[N,K]^T.
// Retained for the LM head only (huge N: B streams; 1 block/CU regime).
// Unchanged from round 12 (passing).
// ---------------------------------------------------------------------------
__device__ __forceinline__ void stage_half(
    const bf_t* __restrict__ src, int row0, int ld, int kt,
    int tid, __bf16* lds_base)
{
  #pragma unroll
  for (int p = 0; p < 2; ++p) {
    const int sb   = p * 512 + (tid & ~63);   // wave-uniform slot base
    const int slot = sb + (tid & 63);
    const int r = slot >> 3;
    const int c = (slot & 7) ^ (r & 7);       // inverse swizzle on global side
    __builtin_amdgcn_global_load_lds(AS1(src + (size_t)(row0 + r) * ld + kt + c * 8),
                                     AS3(lds_base + sb * 8), 16, 0, 0);
  }
}

template<bool HAS_BIAS, bool RELU, bool OUT_BF16, bool NT>
__global__ __launch_bounds__(512, 1) void k_gemm256(
    const bf_t* __restrict__ A, const bf_t* __restrict__ Bt,
    float* outF, bf_t* outB, const float* __restrict__ bias,
    int N, int Nvalid, int K, int nNt)
{
  __shared__ __align__(16) __bf16 LDS[65536];  // A: 4x8192, B: 32768 + 4x8192
  const int tid = threadIdx.x, lane = tid & 63, wid = tid >> 6;
  // A-slab-pinned XCD mapping (bijective: gridDim.x == 16*nNt)
  const int xcd = blockIdx.x & 7;
  const int i   = blockIdx.x >> 3;
  const int g   = i / nNt;
  const int mt  = xcd + 8 * g;
  const int nt  = i - g * nNt;
  const int m0 = mt * 256, n0 = nt * 256;
  if (n0 >= Nvalid) return;                    // LM-head pad tiles
  const int wm = wid >> 2, wn = wid & 3;
  const int l4 = lane & 15, lhi = lane >> 4;

  f32x4 acc[8][4] = {};
  const int NTILES = K >> 6;                   // 16 for K=1024

  // prologue: tiles 0 and 1 (A then B per tile); vmcnt(8) -> tile0 landed
  stage_half(A,  m0,       K, 0,  tid, LDS + 0 * 8192);
  stage_half(A,  m0 + 128, K, 0,  tid, LDS + 1 * 8192);
  stage_half(Bt, n0,       K, 0,  tid, LDS + 32768 + 0 * 8192);
  stage_half(Bt, n0 + 128, K, 0,  tid, LDS + 32768 + 1 * 8192);
  stage_half(A,  m0,       K, 64, tid, LDS + 2 * 8192);
  stage_half(A,  m0 + 128, K, 64, tid, LDS + 3 * 8192);
  stage_half(Bt, n0,       K, 64, tid, LDS + 32768 + 2 * 8192);
  stage_half(Bt, n0 + 128, K, 64, tid, LDS + 32768 + 3 * 8192);
  asm volatile("s_waitcnt vmcnt(8)" ::: "memory");
  __builtin_amdgcn_s_barrier();
  asm volatile("" ::: "memory");

  for (int t = 0; t < NTILES; ++t) {
    const int d = t & 1;
    const __bf16* Abase = LDS + (d * 2 + wm) * 8192;
    const __bf16* Bbase = LDS + 32768 + (d * 2 + (wn >> 1)) * 8192;
    bf16x8 bq[4][2];
    #pragma unroll
    for (int q = 0; q < 4; ++q) {
      // --- phase ds_reads (before first barrier; data valid since tile entry)
      if (q == 0) {
        #pragma unroll
        for (int ni = 0; ni < 4; ++ni) {
          const int r = (wn & 1) * 64 + ni * 16 + l4;
          bq[ni][0] = *(const bf16x8*)&Bbase[r * 64 + ((lhi ^ (r & 7)) * 8)];
          bq[ni][1] = *(const bf16x8*)&Bbase[r * 64 + (((4 + lhi) ^ (r & 7)) * 8)];
        }
      }
      bf16x8 aq[2][2];
      #pragma unroll
      for (int mi2 = 0; mi2 < 2; ++mi2) {
        const int r = (q * 2 + mi2) * 16 + l4;
        aq[mi2][0] = *(const bf16x8*)&Abase[r * 64 + ((lhi ^ (r & 7)) * 8)];
        aq[mi2][1] = *(const bf16x8*)&Abase[r * 64 + (((4 + lhi) ^ (r & 7)) * 8)];
      }
      // --- phase stage (1 half-tile)
      if (q == 0 && t >= 1 && t + 1 < NTILES)
        stage_half(A, m0, K, (t + 1) * 64, tid,
                   LDS + (((t + 1) & 1) * 2 + 0) * 8192);
      if (q == 1 && t >= 1 && t + 1 < NTILES)
        stage_half(A, m0 + 128, K, (t + 1) * 64, tid,
                   LDS + (((t + 1) & 1) * 2 + 1) * 8192);
      if (q == 2 && t + 2 < NTILES)
        stage_half(Bt, n0, K, (t + 2) * 64, tid,
                   LDS + 32768 + (((t + 2) & 1) * 2 + 0) * 8192);
      if (q == 3 && t + 2 < NTILES)
        stage_half(Bt, n0 + 128, K, (t + 2) * 64, tid,
                   LDS + 32768 + (((t + 2) & 1) * 2 + 1) * 8192);
      // --- barrier, pinned lgkm drain, MFMA cluster
      __builtin_amdgcn_s_barrier();
      asm volatile("s_waitcnt lgkmcnt(0)" ::: "memory");
      __builtin_amdgcn_sched_barrier(0);
      __builtin_amdgcn_s_setprio(1);
      #pragma unroll
      for (int mi2 = 0; mi2 < 2; ++mi2)
        #pragma unroll
        for (int ni = 0; ni < 4; ++ni) {
          acc[q * 2 + mi2][ni] = __builtin_amdgcn_mfma_f32_16x16x32_bf16(
              aq[mi2][0], bq[ni][0], acc[q * 2 + mi2][ni], 0, 0, 0);
          acc[q * 2 + mi2][ni] = __builtin_amdgcn_mfma_f32_16x16x32_bf16(
              aq[mi2][1], bq[ni][1], acc[q * 2 + mi2][ni], 0, 0, 0);
        }
      __builtin_amdgcn_s_setprio(0);
      // --- boundary vmcnt (counted; never 0 mid-loop) + end barrier
      if (q == 3) {
        if (t + 2 < NTILES) asm volatile("s_waitcnt vmcnt(4)" ::: "memory");
        else                asm volatile("s_waitcnt vmcnt(0)" ::: "memory");
      }
      __builtin_amdgcn_s_barrier();
      asm volatile("" ::: "memory");
    }
  }

  // ---- epilogue: wave-private LDS slab -> FULL-LINE coalesced stores ----
  float* slab = (float*)LDS + wid * 1088;      // 16 rows x pitch 68
  float bval[4];
  if (HAS_BIAS) {
    #pragma unroll
    for (int ni = 0; ni < 4; ++ni) bval[ni] = bias[n0 + wn * 64 + ni * 16 + l4];
  }
  #pragma unroll
  for (int mi = 0; mi < 8; ++mi) {
    #pragma unroll
    for (int ni = 0; ni < 4; ++ni)
      #pragma unroll
      for (int j = 0; j < 4; ++j) {
        float v = acc[mi][ni][j];
        if (HAS_BIAS) v += bval[ni];
        if (RELU) v = fmaxf(v, 0.f);
        slab[(lhi * 4 + j) * 68 + ni * 16 + l4] = v;   // C/D: row=lhi*4+j, col=l4
      }
    const int grow0 = m0 + wm * 128 + mi * 16;
    const int ncol0 = n0 + wn * 64;
    #pragma unroll
    for (int q = 0; q < 4; ++q) {
      const int r16 = q * 4 + lhi;
      const f32x4 v = *(const f32x4*)&slab[r16 * 68 + l4 * 4];
      const size_t gaddr = (size_t)(grow0 + r16) * N + ncol0 + l4 * 4;
      if (OUT_BF16) {
        bf16x4 o4;
        o4[0] = (__bf16)v[0]; o4[1] = (__bf16)v[1];
        o4[2] = (__bf16)v[2]; o4[3] = (__bf16)v[3];
        *(bf16x4*)(outB + gaddr) = o4;
      } else if (NT) {
        __builtin_nontemporal_store(v, (f32x4*)(outF + gaddr));
      } else {
        *(f32x4*)(outF + gaddr) = v;
      }
    }
  }
}

// ---------------------------------------------------------------------------
// MFMA flash attention, QBLK=128 (8 waves, 512 thr).  Unchanged (passing).
// ---------------------------------------------------------------------------
__global__ __launch_bounds__(512) void k_attn_mfma(
    const bf_t* __restrict__ qkv, bf_t* __restrict__ o)
{
  __shared__ __bf16 Qs[128 * 64];
  __shared__ __bf16 Ks[64 * 64];
  __shared__ __bf16 Vt[64 * 64];
  __shared__ __bf16 Ps[8][16 * 64];

  const int qt = blockIdx.x, bh = blockIdx.y;
  const int b = bh >> 4, h = bh & 15;
  const int tid = threadIdx.x, lane = tid & 63, wid = tid >> 6;
  const int qbase = qt * 128;
  const int r0 = wid * 16;
  const int l4 = lane & 15, lhi = lane >> 4;

  #pragma unroll
  for (int p = 0; p < 2; ++p) {
    const int idx = p * 512 + tid;
    const int r = idx >> 3, c8 = idx & 7;
    const bf16x8 v = *(const bf16x8*)(qkv + (size_t)(b * S_ + qbase + r) * 3072 + h * 64 + c8 * 8);
    *(bf16x8*)&Qs[r * 64 + ((c8 ^ (r & 7)) * 8)] = v;
  }

  f32x4 oa[4];
  #pragma unroll
  for (int di = 0; di < 4; ++di) oa[di] = (f32x4){0.f, 0.f, 0.f, 0.f};
  float mrow = -1e30f, lrow = 0.f;

  const float SCL = 0.125f * 1.44269504089f;

  const int lastkt = 2 * qt + 1;
  for (int kt = 0; kt <= lastkt; ++kt) {
    __syncthreads();
    {   // stage K,V tile (64 rows x 8 chunks = 512 = one pass of 512 thr)
      const int r = tid >> 3, c8 = tid & 7;
      const size_t gbase = (size_t)(b * S_ + kt * 64 + r) * 3072 + h * 64 + c8 * 8;
      const bf16x8 kv = *(const bf16x8*)(qkv + gbase + 1024);
      *(bf16x8*)&Ks[r * 64 + ((c8 ^ (r & 7)) * 8)] = kv;
      const bf16x8 vv = *(const bf16x8*)(qkv + gbase + 2048);
      #pragma unroll
      for (int i = 0; i < 8; ++i) {   // transpose-scatter: d = c8*8+i
        const int d = c8 * 8 + i;
        Vt[d * 64 + (((r >> 3) ^ i ^ c8) * 8) + (r & 7)] = vv[i];
      }
    }
    __syncthreads();

    // --- swapped QK^T: s[ni] holds S^T[t][q], t=ni*16+lhi*4+j, q=r0+l4 ---
    f32x4 s[4];
    #pragma unroll
    for (int ni = 0; ni < 4; ++ni) s[ni] = (f32x4){0.f, 0.f, 0.f, 0.f};
    const int qr = r0 + l4;
    __builtin_amdgcn_s_setprio(1);
    #pragma unroll
    for (int kk = 0; kk < 2; ++kk) {
      const int ck = kk * 4 + lhi;
      const bf16x8 bq = *(const bf16x8*)&Qs[qr * 64 + ((ck ^ (qr & 7)) * 8)];
      #pragma unroll
      for (int ni = 0; ni < 4; ++ni) {
        const int t = ni * 16 + l4;
        const bf16x8 ak = *(const bf16x8*)&Ks[t * 64 + ((ck ^ (t & 7)) * 8)];
        s[ni] = __builtin_amdgcn_mfma_f32_16x16x32_bf16(ak, bq, s[ni], 0, 0, 0);
      }
    }
    __builtin_amdgcn_s_setprio(0);

    // scale into log2 domain; mask when this tile touches/passes the diagonal
    #pragma unroll
    for (int ni = 0; ni < 4; ++ni)
      #pragma unroll
      for (int j = 0; j < 4; ++j)
        s[ni][j] *= SCL;
    if (kt >= 2 * qt) {
      const int dq = qbase + r0 + l4 - kt * 64;   // may be negative (all-masked)
      #pragma unroll
      for (int ni = 0; ni < 4; ++ni)
        #pragma unroll
        for (int j = 0; j < 4; ++j)
          if (ni * 16 + lhi * 4 + j > dq) s[ni][j] = -1e30f;
    }

    // --- online softmax, q = l4 lane-local; combine across lhi via 2 shfl ---
    float mloc = -1e30f;
    #pragma unroll
    for (int ni = 0; ni < 4; ++ni)
      #pragma unroll
      for (int j = 0; j < 4; ++j) mloc = fmaxf(mloc, s[ni][j]);
    mloc = fmaxf(mloc, __shfl_xor(mloc, 16));
    mloc = fmaxf(mloc, __shfl_xor(mloc, 32));
    float cscale = 1.f;
    if (!__all(mloc <= mrow + 8.f)) {   // T13 defer-max
      const float mnew = fmaxf(mrow, mloc);
      cscale = exp2f(mrow - mnew);
      #pragma unroll
      for (int j = 0; j < 4; ++j) {
        const float cj = __shfl(cscale, lhi * 4 + j);
        #pragma unroll
        for (int di = 0; di < 4; ++di) oa[di][j] *= cj;
      }
      mrow = mnew;
    }
    float ssum = 0.f;
    #pragma unroll
    for (int ni = 0; ni < 4; ++ni)
      #pragma unroll
      for (int j = 0; j < 4; ++j) {
        const float pv = exp2f(s[ni][j] - mrow);
        s[ni][j] = pv;
        ssum += pv;
      }
    ssum += __shfl_xor(ssum, 16);
    ssum += __shfl_xor(ssum, 32);
    lrow = lrow * cscale + ssum;

    // --- P -> wave-private LDS: P[q=l4][t=ni*16+lhi*4+j], swizzled ---
    #pragma unroll
    for (int ni = 0; ni < 4; ++ni)
      #pragma unroll
      for (int j = 0; j < 4; ++j) {
        const int c = ni * 16 + lhi * 4 + j;
        Ps[wid][l4 * 64 + (((c >> 3) ^ (l4 & 7)) * 8) + (c & 7)] = (__bf16)s[ni][j];
      }

    // --- PV: O(16x64) += P(16x64) * V(64x64), B-operand = Vt rows (d) ---
    __builtin_amdgcn_s_setprio(1);
    #pragma unroll
    for (int kk = 0; kk < 2; ++kk) {
      const int ck = kk * 4 + lhi;
      const bf16x8 ap = *(const bf16x8*)&Ps[wid][l4 * 64 + ((ck ^ (l4 & 7)) * 8)];
      #pragma unroll
      for (int di = 0; di < 4; ++di) {
        const int d = di * 16 + l4;
        const bf16x8 bv = *(const bf16x8*)&Vt[d * 64 + ((ck ^ (d & 7) ^ ((d >> 3) & 7)) * 8)];
        oa[di] = __builtin_amdgcn_mfma_f32_16x16x32_bf16(ap, bv, oa[di], 0, 0, 0);
      }
    }
    __builtin_amdgcn_s_setprio(0);
  }

  // epilogue: normalize and store bf16 (row q = r0 + lhi*4 + j, col = di*16+l4)
  #pragma unroll
  for (int j = 0; j < 4; ++j) {
    const float lj = __shfl(lrow, lhi * 4 + j);
    const float inv = 1.f / lj;
    const size_t row = (size_t)(b * S_) + qbase + r0 + lhi * 4 + j;
    #pragma unroll
    for (int di = 0; di < 4; ++di)
      o[row * 1024 + h * 64 + di * 16 + l4] = __float2bfloat16(oa[di][j] * inv);
  }
}

// ---------------------------------------------------------------------------
extern "C" void kernel_launch(void* const* d_in, const int* in_sizes, int n_in,
                              void* d_out, int out_size, void* d_ws, size_t ws_size,
                              hipStream_t stream)
{
  (void)in_sizes; (void)n_in; (void)out_size; (void)ws_size;
  const int*   idx  = (const int*)  d_in[0];
  const float* tok  = (const float*)d_in[1];
  const float* pos  = (const float*)d_in[2];
  const float* wq   = (const float*)d_in[3];
  const float* wk   = (const float*)d_in[4];
  const float* wv   = (const float*)d_in[5];
  const float* wo   = (const float*)d_in[6];
  const float* w1   = (const float*)d_in[7];
  const float* b1   = (const float*)d_in[8];
  const float* w2   = (const float*)d_in[9];
  const float* b2   = (const float*)d_in[10];
  const float* ln1g = (const float*)d_in[11];
  const float* ln1b = (const float*)d_in[12];
  const float* ln2g = (const float*)d_in[13];
  const float* ln2b = (const float*)d_in[14];
  const float* lnfg = (const float*)d_in[15];
  const float* lnfb = (const float*)d_in[16];
  const float* lmw  = (const float*)d_in[17];
  const float* lmb  = (const float*)d_in[18];
  float* out = (float*)d_out;

  char* ws = (char*)d_ws;
  size_t off = 0;
  auto alloc = [&](size_t bytes) {
    void* p = ws + off; off += (bytes + 255) & ~(size_t)255; return p;
  };
  bf_t*  qkvw = (bf_t*) alloc((size_t)L_ * 3072 * 1024 * 2);
  bf_t*  wot  = (bf_t*) alloc((size_t)L_ * 1024 * 1024 * 2);
  bf_t*  w1t  = (bf_t*) alloc((size_t)L_ * 4096 * 1024 * 2);
  bf_t*  w2t  = (bf_t*) alloc((size_t)L_ * 1024 * 4096 * 2);
  bf_t*  lmwt = (bf_t*) alloc((size_t)VP_ * 1024 * 2);
  float* x    = (float*)alloc((size_t)M_ * D_ * 4);
  bf_t*  hbuf = (bf_t*) alloc((size_t)M_ * D_ * 2);
  bf_t*  qkvb = (bf_t*) alloc((size_t)M_ * 3072 * 2);
  bf_t*  attb = (bf_t*) alloc((size_t)M_ * D_ * 2);
  bf_t*  ffnb = (bf_t*) alloc((size_t)M_ * DFF_ * 2);
  float* PpartO = (float*)ffnb;   // outproj partials: ffnb dead here
  float* PpartF = (float*)qkvb;   // FFN2 partials: qkvb+attb dead here
  const long PSTRIDE = (long)M_ * 1024;

  const dim3 tb(32, 8);
  k_transpose_bf16<<<dim3(2, 32, L_*H_), tb, 0, stream>>>(
      wq, qkvw + 0 * 1024 * 1024, D_, 64,
      (long)H_*D_*64, (long)D_*64, (long)3*1024*1024, (long)64*1024, H_);
  k_transpose_bf16<<<dim3(2, 32, L_*H_), tb, 0, stream>>>(
      wk, qkvw + 1 * 1024 * 1024, D_, 64,
      (long)H_*D_*64, (long)D_*64, (long)3*1024*1024, (long)64*1024, H_);
  k_transpose_bf16<<<dim3(2, 32, L_*H_), tb, 0, stream>>>(
      wv, qkvw + 2 * 1024 * 1024, D_, 64,
      (long)H_*D_*64, (long)D_*64, (long)3*1024*1024, (long)64*1024, H_);
  k_transpose_bf16<<<dim3(32, 32, L_), tb, 0, stream>>>(
      wo, wot, 1024, 1024, (long)1024*1024, 0, (long)1024*1024, 0, 1);
  k_transpose_bf16<<<dim3(128, 32, L_), tb, 0, stream>>>(
      w1, w1t, 1024, 4096, (long)1024*4096, 0, (long)1024*4096, 0, 1);
  k_transpose_bf16<<<dim3(32, 128, L_), tb, 0, stream>>>(
      w2, w2t, 4096, 1024, (long)4096*1024, 0, (long)4096*1024, 0, 1);
  k_transpose_bf16<<<dim3(1000, 32, 1), tb, 0, stream>>>(
      lmw, lmwt, 1024, V_, 0, 0, 0, 0, 1);

  k_embed<<<M_, 256, 0, stream>>>(idx, tok, pos, x);
  k_ln<<<M_, 256, 0, stream>>>(x, ln1g, ln1b, hbuf);   // layer-0 ln1

  for (int l = 0; l < L_; ++l) {
    // QKV: [4096,1024] x [3072,1024]^T -> bf16  (128² dbuf, 768 blocks, 3/CU)
    k_gemm<false, false, true, false, 1><<<32 * 24, 256, 0, stream>>>(
        hbuf, qkvw + (size_t)l * 3072 * 1024, nullptr, qkvb, nullptr,
        3072, 1024, 1024, 0);
    k_attn_mfma<<<dim3(S_ / 128, B_ * H_), 512, 0, stream>>>(qkvb, attb);
    // out-proj, split-K=2 (128² dbuf kernel) ; fused combine + ln2
    k_gemm<false, false, false, false, 2><<<2 * 8 * 32, 256, 0, stream>>>(
        attb, wot + (size_t)l * 1024 * 1024, PpartO, nullptr, nullptr,
        1024, 1024, 512, PSTRIDE);
    k_combine_ln<<<M_, 256, 0, stream>>>(
        x, PpartO, PSTRIDE, nullptr, ln2g + l * D_, ln2b + l * D_, hbuf);
    // FFN1 + bias + relu -> bf16  (128² dbuf, 1024 blocks, 2-3/CU)
    k_gemm<true, true, true, false, 1><<<32 * 32, 256, 0, stream>>>(
        hbuf, w1t + (size_t)l * 4096 * 1024, nullptr, ffnb, b1 + l * DFF_,
        4096, 1024, 1024, 0);
    // FFN2, split-K=2 (128² dbuf kernel); fused combine(+b2) + next LN
    k_gemm<false, false, false, false, 2><<<2 * 8 * 32, 256, 0, stream>>>(
        ffnb, w2t + (size_t)l * 1024 * 4096, PpartF, nullptr, nullptr,
        1024, 4096, 2048, PSTRIDE);
    const float* ng = (l < L_ - 1) ? (ln1g + (l + 1) * D_) : lnfg;
    const float* nb = (l < L_ - 1) ? (ln1b + (l + 1) * D_) : lnfb;
    k_combine_ln<<<M_, 256, 0, stream>>>(
        x, PpartF, PSTRIDE, b2 + l * D_, ng, nb, hbuf);
  }

  // LM head: 8-phase 256², A-slab-pinned XCD map, full-line NT logit stores.
  k_gemm256<true, false, false, true><<<16 * 128, 512, 0, stream>>>(
      hbuf, lmwt, out, nullptr, lmb,
      V_, V_, 1024, 128);
}

// Round 14
// 1250.850 us; speedup vs baseline: 1.1322x; 1.1322x over previous
//
#include <hip/hip_runtime.h>
#include <hip/hip_bf16.h>

// GPT forward: V=32000 D=1024 S=1024 L=4 H=16 DK=DV=64 B=4 DFF=4096
#define V_   32000
#define VP_  32768     // padded lmwt allocation (rows >= 32000 unused)
#define D_   1024
#define S_   1024
#define L_   4
#define H_   16
#define B_   4
#define DFF_ 4096
#define M_   (B_*S_)   // 4096 token rows

using bf_t = __hip_bfloat16;
typedef __bf16 bf16x8 __attribute__((ext_vector_type(8)));
typedef __bf16 bf16x4 __attribute__((ext_vector_type(4)));
typedef float  f32x4  __attribute__((ext_vector_type(4)));

#define AS1(p) ((__attribute__((address_space(1))) void*)(p))
#define AS3(p) ((__attribute__((address_space(3))) void*)(p))

// ---------------------------------------------------------------------------
// Transpose f32 [R,C] -> bf16 [C,R], batched over two strides (z = z1*n2+z2)
// ---------------------------------------------------------------------------
__global__ __launch_bounds__(256) void k_transpose_bf16(
    const float* __restrict__ src, bf_t* __restrict__ dst,
    int R, int C, long srcS1, long srcS2, long dstS1, long dstS2, int n2)
{
  const int z  = blockIdx.z;
  const int z1 = z / n2, z2 = z % n2;
  src += (size_t)z1 * srcS1 + (size_t)z2 * srcS2;
  dst += (size_t)z1 * dstS1 + (size_t)z2 * dstS2;
  __shared__ float tile[32][33];
  const int c0 = blockIdx.x * 32, r0 = blockIdx.y * 32;
  const int lx = threadIdx.x, ly = threadIdx.y;  // 32 x 8
  #pragma unroll
  for (int i = 0; i < 32; i += 8)
    tile[ly + i][lx] = src[(size_t)(r0 + ly + i) * C + (c0 + lx)];
  __syncthreads();
  #pragma unroll
  for (int i = 0; i < 32; i += 8)
    dst[(size_t)(c0 + ly + i) * R + (r0 + lx)] = __float2bfloat16(tile[lx][ly + i]);
}

// ---------------------------------------------------------------------------
// Embedding: x[b,s,:] = tok_emb[idx[b,s],:] + pos_emb[s,:]
// ---------------------------------------------------------------------------
__global__ __launch_bounds__(256) void k_embed(
    const int* __restrict__ idx, const float* __restrict__ tok,
    const float* __restrict__ pos, float* __restrict__ x)
{
  const int row = blockIdx.x;          // b*S + s
  const int s   = row & (S_ - 1);
  const int t   = idx[row];
  const float4* tr = (const float4*)(tok + (size_t)t * D_);
  const float4* pr = (const float4*)(pos + (size_t)s * D_);
  float4* xr = (float4*)(x + (size_t)row * D_);
  const int i = threadIdx.x;
  float4 a = tr[i], b = pr[i];
  xr[i] = make_float4(a.x + b.x, a.y + b.y, a.z + b.z, a.w + b.w);
}

// ---------------------------------------------------------------------------
// LayerNorm (f32 in) -> bf16 out.  One block (256 thr) per row, D=1024.
// ---------------------------------------------------------------------------
__global__ __launch_bounds__(256) void k_ln(
    const float* __restrict__ x, const float* __restrict__ g,
    const float* __restrict__ bb, bf_t* __restrict__ out)
{
  __shared__ float red[8];
  const int row = blockIdx.x, tid = threadIdx.x;
  const float4 v = ((const float4*)(x + (size_t)row * D_))[tid];
  float s = v.x + v.y + v.z + v.w;
  #pragma unroll
  for (int o = 32; o > 0; o >>= 1) s += __shfl_down(s, o);
  if ((tid & 63) == 0) red[tid >> 6] = s;
  __syncthreads();
  const float mu = (red[0] + red[1] + red[2] + red[3]) * (1.f / D_);
  const float dx = v.x - mu, dy = v.y - mu, dz = v.z - mu, dw = v.w - mu;
  float ss = dx*dx + dy*dy + dz*dz + dw*dw;
  #pragma unroll
  for (int o = 32; o > 0; o >>= 1) ss += __shfl_down(ss, o);
  if ((tid & 63) == 0) red[4 + (tid >> 6)] = ss;
  __syncthreads();
  const float var = (red[4] + red[5] + red[6] + red[7]) * (1.f / D_);
  const float rs  = rsqrtf(var + 1e-5f);
  const float4 gv = ((const float4*)g)[tid];
  const float4 bv = ((const float4*)bb)[tid];
  const size_t base = (size_t)row * D_ + tid * 4;
  out[base + 0] = __float2bfloat16(dx * rs * gv.x + bv.x);
  out[base + 1] = __float2bfloat16(dy * rs * gv.y + bv.y);
  out[base + 2] = __float2bfloat16(dz * rs * gv.z + bv.z);
  out[base + 3] = __float2bfloat16(dw * rs * gv.w + bv.w);
}

// ---------------------------------------------------------------------------
// Fused split-K combine + LayerNorm:
//   x[row] += P0[row] + P1[row] (+ cbias);  out[row] = LN(x[row]) (bf16)
// ---------------------------------------------------------------------------
__global__ __launch_bounds__(256) void k_combine_ln(
    float* __restrict__ x, const float* __restrict__ P, long pstride,
    const float* __restrict__ cbias,
    const float* __restrict__ g, const float* __restrict__ bb,
    bf_t* __restrict__ out)
{
  __shared__ float red[8];
  const int row = blockIdx.x, tid = threadIdx.x;
  const size_t i = (size_t)row * 256 + tid;
  float4 a = ((const float4*)x)[i];
  {
    const float4 p0 = ((const float4*)P)[i];
    const float4 p1 = ((const float4*)(P + pstride))[i];
    a.x += p0.x + p1.x; a.y += p0.y + p1.y;
    a.z += p0.z + p1.z; a.w += p0.w + p1.w;
  }
  if (cbias) {
    const float4 bv = ((const float4*)cbias)[tid];
    a.x += bv.x; a.y += bv.y; a.z += bv.z; a.w += bv.w;
  }
  ((float4*)x)[i] = a;
  float s = a.x + a.y + a.z + a.w;
  #pragma unroll
  for (int o = 32; o > 0; o >>= 1) s += __shfl_down(s, o);
  if ((tid & 63) == 0) red[tid >> 6] = s;
  __syncthreads();
  const float mu = (red[0] + red[1] + red[2] + red[3]) * (1.f / D_);
  const float dx = a.x - mu, dy = a.y - mu, dz = a.z - mu, dw = a.w - mu;
  float ss = dx*dx + dy*dy + dz*dz + dw*dw;
  #pragma unroll
  for (int o = 32; o > 0; o >>= 1) ss += __shfl_down(ss, o);
  if ((tid & 63) == 0) red[4 + (tid >> 6)] = ss;
  __syncthreads();
  const float var = (red[4] + red[5] + red[6] + red[7]) * (1.f / D_);
  const float rs  = rsqrtf(var + 1e-5f);
  const float4 gv = ((const float4*)g)[tid];
  const float4 bv = ((const float4*)bb)[tid];
  const size_t base = (size_t)row * D_ + tid * 4;
  out[base + 0] = __float2bfloat16(dx * rs * gv.x + bv.x);
  out[base + 1] = __float2bfloat16(dy * rs * gv.y + bv.y);
  out[base + 2] = __float2bfloat16(dz * rs * gv.z + bv.z);
  out[base + 3] = __float2bfloat16(dw * rs * gv.w + bv.w);
}

// ---------------------------------------------------------------------------
// 128x128 GEMM — split-K small-N cases only (out-proj, FFN2).
// Double-buffered LDS + 1-tile-deep prefetch + XOR swizzle.  (Round-13's
// use for QKV/FFN1 regressed; reverted to round-12 usage.)
// ---------------------------------------------------------------------------
template<bool HAS_BIAS, bool RELU, bool OUT_BF16, bool NT, int PARTS>
__global__ __launch_bounds__(256) void k_gemm(
    const bf_t* __restrict__ A, const bf_t* __restrict__ Bt,
    float* outF, bf_t* outB,
    const float* __restrict__ bias,
    int N, int ld, int Klen, long pstride)
{
  __shared__ __bf16 As[2][128 * 64];
  __shared__ __bf16 Bs[2][128 * 64];
  const int tid  = threadIdx.x;
  const int lane = tid & 63, wid = tid >> 6;
  int bp = blockIdx.x, kh = 0;
  if (PARTS > 1) { const int T = gridDim.x / PARTS; kh = bp / T; bp %= T; }
  const int i  = bp >> 3;
  const int nt = (bp & 7) + 8 * (i >> 5);
  const int mt = i & 31;
  const int m0 = mt * 128;
  const int n0 = nt * 128;
  if (n0 >= N) return;
  const int kb = kh * Klen;
  f32x4 acc[4][4] = {};

  const int srow = lane >> 3;
  const int scol = ((lane & 7) ^ (lane >> 3)) * 8;
  const int mw = (wid >> 1) * 64, nw = (wid & 1) * 64;
  const int NTk = Klen >> 6;

  #pragma unroll
  for (int i2 = 0; i2 < 4; ++i2) {
    const int chunk = i2 * 4 + wid;
    const int r = chunk * 8 + srow;
    __builtin_amdgcn_global_load_lds(AS1(A  + (size_t)(m0 + r) * ld + kb + scol),
                                     AS3(&As[0][chunk * 512]), 16, 0, 0);
    __builtin_amdgcn_global_load_lds(AS1(Bt + (size_t)(n0 + r) * ld + kb + scol),
                                     AS3(&Bs[0][chunk * 512]), 16, 0, 0);
  }

  for (int t = 0; t < NTk; ++t) {
    __syncthreads();   // implicit vmcnt(0): stage(t) landed for ALL waves
    if (t + 1 < NTk) {
      const int kt = (t + 1) << 6;
      #pragma unroll
      for (int i2 = 0; i2 < 4; ++i2) {
        const int chunk = i2 * 4 + wid;
        const int r = chunk * 8 + srow;
        __builtin_amdgcn_global_load_lds(AS1(A  + (size_t)(m0 + r) * ld + kb + kt + scol),
                                         AS3(&As[(t + 1) & 1][chunk * 512]), 16, 0, 0);
        __builtin_amdgcn_global_load_lds(AS1(Bt + (size_t)(n0 + r) * ld + kb + kt + scol),
                                         AS3(&Bs[(t + 1) & 1][chunk * 512]), 16, 0, 0);
      }
    }
    const __bf16* Ab = As[t & 1];
    const __bf16* Bb = Bs[t & 1];
    #pragma unroll
    for (int kk = 0; kk < 2; ++kk) {
      const int ck = kk * 4 + (lane >> 4);
      bf16x8 af[4], bfr[4];
      #pragma unroll
      for (int mi = 0; mi < 4; ++mi) {
        const int r = mw + mi * 16 + (lane & 15);
        af[mi] = *(const bf16x8*)&Ab[r * 64 + ((ck ^ (r & 7)) * 8)];
      }
      #pragma unroll
      for (int ni = 0; ni < 4; ++ni) {
        const int r = nw + ni * 16 + (lane & 15);
        bfr[ni] = *(const bf16x8*)&Bb[r * 64 + ((ck ^ (r & 7)) * 8)];
      }
      #pragma unroll
      for (int mi = 0; mi < 4; ++mi)
        #pragma unroll
        for (int ni = 0; ni < 4; ++ni)
          acc[mi][ni] = __builtin_amdgcn_mfma_f32_16x16x32_bf16(af[mi], bfr[ni], acc[mi][ni], 0, 0, 0);
    }
  }

  float* outP = outF + (PARTS > 1 ? (size_t)kh * pstride : 0);
  const int cr = (lane >> 4) * 4, cc = lane & 15;
  #pragma unroll
  for (int mi = 0; mi < 4; ++mi) {
    #pragma unroll
    for (int ni = 0; ni < 4; ++ni) {
      const int col = n0 + nw + ni * 16 + cc;
      const float bv = HAS_BIAS ? bias[col] : 0.f;
      #pragma unroll
      for (int j = 0; j < 4; ++j) {
        const int row = m0 + mw + mi * 16 + cr + j;
        float v = acc[mi][ni][j] + bv;
        if (RELU)  v = fmaxf(v, 0.f);
        if (OUT_BF16) {
          outB[(size_t)row * N + col] = __float2bfloat16(v);
        } else if (NT) {
          __builtin_nontemporal_store(v, &outP[(size_t)row * N + col]);
        } else {
          outP[(size_t)row * N + col] = v;
        }
      }
    }
  }
}

// ---------------------------------------------------------------------------
// 256x256 8-PHASE deep-pipelined GEMM (T2+T3+T4+T5), C = A[M,K]*Bt[N,K]^T.
// Used for QKV, FFN1 (reverted: round-13's 128² swap regressed) and LM head.
// Unchanged from round 12 (passing, ~800 TF on the LM head).
// ---------------------------------------------------------------------------
__device__ __forceinline__ void stage_half(
    const bf_t* __restrict__ src, int row0, int ld, int kt,
    int tid, __bf16* lds_base)
{
  #pragma unroll
  for (int p = 0; p < 2; ++p) {
    const int sb   = p * 512 + (tid & ~63);   // wave-uniform slot base
    const int slot = sb + (tid & 63);
    const int r = slot >> 3;
    const int c = (slot & 7) ^ (r & 7);       // inverse swizzle on global side
    __builtin_amdgcn_global_load_lds(AS1(src + (size_t)(row0 + r) * ld + kt + c * 8),
                                     AS3(lds_base + sb * 8), 16, 0, 0);
  }
}

template<bool HAS_BIAS, bool RELU, bool OUT_BF16, bool NT>
__global__ __launch_bounds__(512, 1) void k_gemm256(
    const bf_t* __restrict__ A, const bf_t* __restrict__ Bt,
    float* outF, bf_t* outB, const float* __restrict__ bias,
    int N, int Nvalid, int K, int nNt)
{
  __shared__ __align__(16) __bf16 LDS[65536];  // A: 4x8192, B: 32768 + 4x8192
  const int tid = threadIdx.x, lane = tid & 63, wid = tid >> 6;
  // A-slab-pinned XCD mapping (bijective: gridDim.x == 16*nNt)
  const int xcd = blockIdx.x & 7;
  const int i   = blockIdx.x >> 3;
  const int g   = i / nNt;
  const int mt  = xcd + 8 * g;
  const int nt  = i - g * nNt;
  const int m0 = mt * 256, n0 = nt * 256;
  if (n0 >= Nvalid) return;                    // LM-head pad tiles
  const int wm = wid >> 2, wn = wid & 3;
  const int l4 = lane & 15, lhi = lane >> 4;

  f32x4 acc[8][4] = {};
  const int NTILES = K >> 6;                   // 16 for K=1024

  // prologue: tiles 0 and 1 (A then B per tile); vmcnt(8) -> tile0 landed
  stage_half(A,  m0,       K, 0,  tid, LDS + 0 * 8192);
  stage_half(A,  m0 + 128, K, 0,  tid, LDS + 1 * 8192);
  stage_half(Bt, n0,       K, 0,  tid, LDS + 32768 + 0 * 8192);
  stage_half(Bt, n0 + 128, K, 0,  tid, LDS + 32768 + 1 * 8192);
  stage_half(A,  m0,       K, 64, tid, LDS + 2 * 8192);
  stage_half(A,  m0 + 128, K, 64, tid, LDS + 3 * 8192);
  stage_half(Bt, n0,       K, 64, tid, LDS + 32768 + 2 * 8192);
  stage_half(Bt, n0 + 128, K, 64, tid, LDS + 32768 + 3 * 8192);
  asm volatile("s_waitcnt vmcnt(8)" ::: "memory");
  __builtin_amdgcn_s_barrier();
  asm volatile("" ::: "memory");

  for (int t = 0; t < NTILES; ++t) {
    const int d = t & 1;
    const __bf16* Abase = LDS + (d * 2 + wm) * 8192;
    const __bf16* Bbase = LDS + 32768 + (d * 2 + (wn >> 1)) * 8192;
    bf16x8 bq[4][2];
    #pragma unroll
    for (int q = 0; q < 4; ++q) {
      // --- phase ds_reads (before first barrier; data valid since tile entry)
      if (q == 0) {
        #pragma unroll
        for (int ni = 0; ni < 4; ++ni) {
          const int r = (wn & 1) * 64 + ni * 16 + l4;
          bq[ni][0] = *(const bf16x8*)&Bbase[r * 64 + ((lhi ^ (r & 7)) * 8)];
          bq[ni][1] = *(const bf16x8*)&Bbase[r * 64 + (((4 + lhi) ^ (r & 7)) * 8)];
        }
      }
      bf16x8 aq[2][2];
      #pragma unroll
      for (int mi2 = 0; mi2 < 2; ++mi2) {
        const int r = (q * 2 + mi2) * 16 + l4;
        aq[mi2][0] = *(const bf16x8*)&Abase[r * 64 + ((lhi ^ (r & 7)) * 8)];
        aq[mi2][1] = *(const bf16x8*)&Abase[r * 64 + (((4 + lhi) ^ (r & 7)) * 8)];
      }
      // --- phase stage (1 half-tile)
      if (q == 0 && t >= 1 && t + 1 < NTILES)
        stage_half(A, m0, K, (t + 1) * 64, tid,
                   LDS + (((t + 1) & 1) * 2 + 0) * 8192);
      if (q == 1 && t >= 1 && t + 1 < NTILES)
        stage_half(A, m0 + 128, K, (t + 1) * 64, tid,
                   LDS + (((t + 1) & 1) * 2 + 1) * 8192);
      if (q == 2 && t + 2 < NTILES)
        stage_half(Bt, n0, K, (t + 2) * 64, tid,
                   LDS + 32768 + (((t + 2) & 1) * 2 + 0) * 8192);
      if (q == 3 && t + 2 < NTILES)
        stage_half(Bt, n0 + 128, K, (t + 2) * 64, tid,
                   LDS + 32768 + (((t + 2) & 1) * 2 + 1) * 8192);
      // --- barrier, pinned lgkm drain, MFMA cluster
      __builtin_amdgcn_s_barrier();
      asm volatile("s_waitcnt lgkmcnt(0)" ::: "memory");
      __builtin_amdgcn_sched_barrier(0);
      __builtin_amdgcn_s_setprio(1);
      #pragma unroll
      for (int mi2 = 0; mi2 < 2; ++mi2)
        #pragma unroll
        for (int ni = 0; ni < 4; ++ni) {
          acc[q * 2 + mi2][ni] = __builtin_amdgcn_mfma_f32_16x16x32_bf16(
              aq[mi2][0], bq[ni][0], acc[q * 2 + mi2][ni], 0, 0, 0);
          acc[q * 2 + mi2][ni] = __builtin_amdgcn_mfma_f32_16x16x32_bf16(
              aq[mi2][1], bq[ni][1], acc[q * 2 + mi2][ni], 0, 0, 0);
        }
      __builtin_amdgcn_s_setprio(0);
      // --- boundary vmcnt (counted; never 0 mid-loop) + end barrier
      if (q == 3) {
        if (t + 2 < NTILES) asm volatile("s_waitcnt vmcnt(4)" ::: "memory");
        else                asm volatile("s_waitcnt vmcnt(0)" ::: "memory");
      }
      __builtin_amdgcn_s_barrier();
      asm volatile("" ::: "memory");
    }
  }

  // ---- epilogue: wave-private LDS slab -> FULL-LINE coalesced stores ----
  float* slab = (float*)LDS + wid * 1088;      // 16 rows x pitch 68
  float bval[4];
  if (HAS_BIAS) {
    #pragma unroll
    for (int ni = 0; ni < 4; ++ni) bval[ni] = bias[n0 + wn * 64 + ni * 16 + l4];
  }
  #pragma unroll
  for (int mi = 0; mi < 8; ++mi) {
    #pragma unroll
    for (int ni = 0; ni < 4; ++ni)
      #pragma unroll
      for (int j = 0; j < 4; ++j) {
        float v = acc[mi][ni][j];
        if (HAS_BIAS) v += bval[ni];
        if (RELU) v = fmaxf(v, 0.f);
        slab[(lhi * 4 + j) * 68 + ni * 16 + l4] = v;   // C/D: row=lhi*4+j, col=l4
      }
    const int grow0 = m0 + wm * 128 + mi * 16;
    const int ncol0 = n0 + wn * 64;
    #pragma unroll
    for (int q = 0; q < 4; ++q) {
      const int r16 = q * 4 + lhi;
      const f32x4 v = *(const f32x4*)&slab[r16 * 68 + l4 * 4];
      const size_t gaddr = (size_t)(grow0 + r16) * N + ncol0 + l4 * 4;
      if (OUT_BF16) {
        bf16x4 o4;
        o4[0] = (__bf16)v[0]; o4[1] = (__bf16)v[1];
        o4[2] = (__bf16)v[2]; o4[3] = (__bf16)v[3];
        *(bf16x4*)(outB + gaddr) = o4;
      } else if (NT) {
        __builtin_nontemporal_store(v, (f32x4*)(outF + gaddr));
      } else {
        *(f32x4*)(outF + gaddr) = v;
      }
    }
  }
}

// ---------------------------------------------------------------------------
// MFMA flash attention, QBLK=128 (8 waves, 512 thr).
// ROUND-14: T14 async-STAGE split — prologue loads KV(0) into regs; per tile
// {barrier; ds_write regs; barrier; ISSUE loads KV(kt+1)->regs; compute}.
// Global-load latency hides under QK^T+softmax+PV instead of sitting exposed
// between the two barriers.  Regs private -> no new race surface; the
// ds_write of tile t is after the barrier retiring all readers of t-1.
// ---------------------------------------------------------------------------
__global__ __launch_bounds__(512) void k_attn_mfma(
    const bf_t* __restrict__ qkv, bf_t* __restrict__ o)
{
  __shared__ __bf16 Qs[128 * 64];
  __shared__ __bf16 Ks[64 * 64];
  __shared__ __bf16 Vt[64 * 64];
  __shared__ __bf16 Ps[8][16 * 64];

  const int qt = blockIdx.x, bh = blockIdx.y;
  const int b = bh >> 4, h = bh & 15;
  const int tid = threadIdx.x, lane = tid & 63, wid = tid >> 6;
  const int qbase = qt * 128;
  const int r0 = wid * 16;
  const int l4 = lane & 15, lhi = lane >> 4;

  // stage Q (128 rows x 8 chunks = 1024; 2 passes x 512 threads)
  #pragma unroll
  for (int p = 0; p < 2; ++p) {
    const int idx = p * 512 + tid;
    const int r = idx >> 3, c8 = idx & 7;
    const bf16x8 v = *(const bf16x8*)(qkv + (size_t)(b * S_ + qbase + r) * 3072 + h * 64 + c8 * 8);
    *(bf16x8*)&Qs[r * 64 + ((c8 ^ (r & 7)) * 8)] = v;
  }

  f32x4 oa[4];
  #pragma unroll
  for (int di = 0; di < 4; ++di) oa[di] = (f32x4){0.f, 0.f, 0.f, 0.f};
  float mrow = -1e30f, lrow = 0.f;

  const float SCL = 0.125f * 1.44269504089f;

  // T14 prologue: KV(0) -> regs
  const int rS = tid >> 3, c8S = tid & 7;           // staging coords (512 thr)
  const size_t gstep = (size_t)64 * 3072;           // 64 rows per tile
  size_t gbaseS = (size_t)(b * S_ + rS) * 3072 + h * 64 + c8S * 8;
  bf16x8 kreg = *(const bf16x8*)(qkv + gbaseS + 1024);
  bf16x8 vreg = *(const bf16x8*)(qkv + gbaseS + 2048);

  const int lastkt = 2 * qt + 1;
  for (int kt = 0; kt <= lastkt; ++kt) {
    __syncthreads();                  // all waves done reading prev Ks/Vt
    // write staged regs -> LDS
    *(bf16x8*)&Ks[rS * 64 + ((c8S ^ (rS & 7)) * 8)] = kreg;
    #pragma unroll
    for (int i = 0; i < 8; ++i) {     // transpose-scatter: d = c8S*8+i
      const int d = c8S * 8 + i;
      Vt[d * 64 + (((rS >> 3) ^ i ^ c8S) * 8) + (rS & 7)] = vreg[i];
    }
    __syncthreads();
    // T14: issue next tile's loads now; latency hides under compute below
    if (kt < lastkt) {
      gbaseS += gstep;
      kreg = *(const bf16x8*)(qkv + gbaseS + 1024);
      vreg = *(const bf16x8*)(qkv + gbaseS + 2048);
    }

    // --- swapped QK^T: s[ni] holds S^T[t][q], t=ni*16+lhi*4+j, q=r0+l4 ---
    f32x4 s[4];
    #pragma unroll
    for (int ni = 0; ni < 4; ++ni) s[ni] = (f32x4){0.f, 0.f, 0.f, 0.f};
    const int qr = r0 + l4;
    __builtin_amdgcn_s_setprio(1);
    #pragma unroll
    for (int kk = 0; kk < 2; ++kk) {
      const int ck = kk * 4 + lhi;
      const bf16x8 bq = *(const bf16x8*)&Qs[qr * 64 + ((ck ^ (qr & 7)) * 8)];
      #pragma unroll
      for (int ni = 0; ni < 4; ++ni) {
        const int t = ni * 16 + l4;
        const bf16x8 ak = *(const bf16x8*)&Ks[t * 64 + ((ck ^ (t & 7)) * 8)];
        s[ni] = __builtin_amdgcn_mfma_f32_16x16x32_bf16(ak, bq, s[ni], 0, 0, 0);
      }
    }
    __builtin_amdgcn_s_setprio(0);

    // scale into log2 domain; mask when this tile touches/passes the diagonal
    #pragma unroll
    for (int ni = 0; ni < 4; ++ni)
      #pragma unroll
      for (int j = 0; j < 4; ++j)
        s[ni][j] *= SCL;
    if (kt >= 2 * qt) {
      const int dq = qbase + r0 + l4 - kt * 64;   // may be negative (all-masked)
      #pragma unroll
      for (int ni = 0; ni < 4; ++ni)
        #pragma unroll
        for (int j = 0; j < 4; ++j)
          if (ni * 16 + lhi * 4 + j > dq) s[ni][j] = -1e30f;
    }

    // --- online softmax, q = l4 lane-local; combine across lhi via 2 shfl ---
    float mloc = -1e30f;
    #pragma unroll
    for (int ni = 0; ni < 4; ++ni)
      #pragma unroll
      for (int j = 0; j < 4; ++j) mloc = fmaxf(mloc, s[ni][j]);
    mloc = fmaxf(mloc, __shfl_xor(mloc, 16));
    mloc = fmaxf(mloc, __shfl_xor(mloc, 32));
    float cscale = 1.f;
    if (!__all(mloc <= mrow + 8.f)) {   // T13 defer-max
      const float mnew = fmaxf(mrow, mloc);
      cscale = exp2f(mrow - mnew);
      #pragma unroll
      for (int j = 0; j < 4; ++j) {
        const float cj = __shfl(cscale, lhi * 4 + j);
        #pragma unroll
        for (int di = 0; di < 4; ++di) oa[di][j] *= cj;
      }
      mrow = mnew;
    }
    float ssum = 0.f;
    #pragma unroll
    for (int ni = 0; ni < 4; ++ni)
      #pragma unroll
      for (int j = 0; j < 4; ++j) {
        const float pv = exp2f(s[ni][j] - mrow);
        s[ni][j] = pv;
        ssum += pv;
      }
    ssum += __shfl_xor(ssum, 16);
    ssum += __shfl_xor(ssum, 32);
    lrow = lrow * cscale + ssum;

    // --- P -> wave-private LDS: P[q=l4][t=ni*16+lhi*4+j], swizzled ---
    #pragma unroll
    for (int ni = 0; ni < 4; ++ni)
      #pragma unroll
      for (int j = 0; j < 4; ++j) {
        const int c = ni * 16 + lhi * 4 + j;
        Ps[wid][l4 * 64 + (((c >> 3) ^ (l4 & 7)) * 8) + (c & 7)] = (__bf16)s[ni][j];
      }

    // --- PV: O(16x64) += P(16x64) * V(64x64), B-operand = Vt rows (d) ---
    __builtin_amdgcn_s_setprio(1);
    #pragma unroll
    for (int kk = 0; kk < 2; ++kk) {
      const int ck = kk * 4 + lhi;
      const bf16x8 ap = *(const bf16x8*)&Ps[wid][l4 * 64 + ((ck ^ (l4 & 7)) * 8)];
      #pragma unroll
      for (int di = 0; di < 4; ++di) {
        const int d = di * 16 + l4;
        const bf16x8 bv = *(const bf16x8*)&Vt[d * 64 + ((ck ^ (d & 7) ^ ((d >> 3) & 7)) * 8)];
        oa[di] = __builtin_amdgcn_mfma_f32_16x16x32_bf16(ap, bv, oa[di], 0, 0, 0);
      }
    }
    __builtin_amdgcn_s_setprio(0);
  }

  // epilogue: normalize and store bf16 (row q = r0 + lhi*4 + j, col = di*16+l4)
  #pragma unroll
  for (int j = 0; j < 4; ++j) {
    const float lj = __shfl(lrow, lhi * 4 + j);
    const float inv = 1.f / lj;
    const size_t row = (size_t)(b * S_) + qbase + r0 + lhi * 4 + j;
    #pragma unroll
    for (int di = 0; di < 4; ++di)
      o[row * 1024 + h * 64 + di * 16 + l4] = __float2bfloat16(oa[di][j] * inv);
  }
}

// ---------------------------------------------------------------------------
extern "C" void kernel_launch(void* const* d_in, const int* in_sizes, int n_in,
                              void* d_out, int out_size, void* d_ws, size_t ws_size,
                              hipStream_t stream)
{
  (void)in_sizes; (void)n_in; (void)out_size; (void)ws_size;
  const int*   idx  = (const int*)  d_in[0];
  const float* tok  = (const float*)d_in[1];
  const float* pos  = (const float*)d_in[2];
  const float* wq   = (const float*)d_in[3];
  const float* wk   = (const float*)d_in[4];
  const float* wv   = (const float*)d_in[5];
  const float* wo   = (const float*)d_in[6];
  const float* w1   = (const float*)d_in[7];
  const float* b1   = (const float*)d_in[8];
  const float* w2   = (const float*)d_in[9];
  const float* b2   = (const float*)d_in[10];
  const float* ln1g = (const float*)d_in[11];
  const float* ln1b = (const float*)d_in[12];
  const float* ln2g = (const float*)d_in[13];
  const float* ln2b = (const float*)d_in[14];
  const float* lnfg = (const float*)d_in[15];
  const float* lnfb = (const float*)d_in[16];
  const float* lmw  = (const float*)d_in[17];
  const float* lmb  = (const float*)d_in[18];
  float* out = (float*)d_out;

  char* ws = (char*)d_ws;
  size_t off = 0;
  auto alloc = [&](size_t bytes) {
    void* p = ws + off; off += (bytes + 255) & ~(size_t)255; return p;
  };
  bf_t*  qkvw = (bf_t*) alloc((size_t)L_ * 3072 * 1024 * 2);
  bf_t*  wot  = (bf_t*) alloc((size_t)L_ * 1024 * 1024 * 2);
  bf_t*  w1t  = (bf_t*) alloc((size_t)L_ * 4096 * 1024 * 2);
  bf_t*  w2t  = (bf_t*) alloc((size_t)L_ * 1024 * 4096 * 2);
  bf_t*  lmwt = (bf_t*) alloc((size_t)VP_ * 1024 * 2);
  float* x    = (float*)alloc((size_t)M_ * D_ * 4);
  bf_t*  hbuf = (bf_t*) alloc((size_t)M_ * D_ * 2);
  bf_t*  qkvb = (bf_t*) alloc((size_t)M_ * 3072 * 2);
  bf_t*  attb = (bf_t*) alloc((size_t)M_ * D_ * 2);
  bf_t*  ffnb = (bf_t*) alloc((size_t)M_ * DFF_ * 2);
  float* PpartO = (float*)ffnb;   // outproj partials: ffnb dead here
  float* PpartF = (float*)qkvb;   // FFN2 partials: qkvb+attb dead here
  const long PSTRIDE = (long)M_ * 1024;

  const dim3 tb(32, 8);
  k_transpose_bf16<<<dim3(2, 32, L_*H_), tb, 0, stream>>>(
      wq, qkvw + 0 * 1024 * 1024, D_, 64,
      (long)H_*D_*64, (long)D_*64, (long)3*1024*1024, (long)64*1024, H_);
  k_transpose_bf16<<<dim3(2, 32, L_*H_), tb, 0, stream>>>(
      wk, qkvw + 1 * 1024 * 1024, D_, 64,
      (long)H_*D_*64, (long)D_*64, (long)3*1024*1024, (long)64*1024, H_);
  k_transpose_bf16<<<dim3(2, 32, L_*H_), tb, 0, stream>>>(
      wv, qkvw + 2 * 1024 * 1024, D_, 64,
      (long)H_*D_*64, (long)D_*64, (long)3*1024*1024, (long)64*1024, H_);
  k_transpose_bf16<<<dim3(32, 32, L_), tb, 0, stream>>>(
      wo, wot, 1024, 1024, (long)1024*1024, 0, (long)1024*1024, 0, 1);
  k_transpose_bf16<<<dim3(128, 32, L_), tb, 0, stream>>>(
      w1, w1t, 1024, 4096, (long)1024*4096, 0, (long)1024*4096, 0, 1);
  k_transpose_bf16<<<dim3(32, 128, L_), tb, 0, stream>>>(
      w2, w2t, 4096, 1024, (long)4096*1024, 0, (long)4096*1024, 0, 1);
  k_transpose_bf16<<<dim3(1000, 32, 1), tb, 0, stream>>>(
      lmw, lmwt, 1024, V_, 0, 0, 0, 0, 1);

  k_embed<<<M_, 256, 0, stream>>>(idx, tok, pos, x);
  k_ln<<<M_, 256, 0, stream>>>(x, ln1g, ln1b, hbuf);   // layer-0 ln1

  for (int l = 0; l < L_; ++l) {
    // QKV: [4096,1024] x [3072,1024]^T -> bf16   (8-phase 256², 192 blocks)
    k_gemm256<false, false, true, false><<<16 * 12, 512, 0, stream>>>(
        hbuf, qkvw + (size_t)l * 3072 * 1024, nullptr, qkvb, nullptr,
        3072, 3072, 1024, 12);
    k_attn_mfma<<<dim3(S_ / 128, B_ * H_), 512, 0, stream>>>(qkvb, attb);
    // out-proj, split-K=2 (128² dbuf kernel) ; fused combine + ln2
    k_gemm<false, false, false, false, 2><<<2 * 8 * 32, 256, 0, stream>>>(
        attb, wot + (size_t)l * 1024 * 1024, PpartO, nullptr, nullptr,
        1024, 1024, 512, PSTRIDE);
    k_combine_ln<<<M_, 256, 0, stream>>>(
        x, PpartO, PSTRIDE, nullptr, ln2g + l * D_, ln2b + l * D_, hbuf);
    // FFN1 + bias + relu -> bf16   (8-phase 256², 256 blocks)
    k_gemm256<true, true, true, false><<<16 * 16, 512, 0, stream>>>(
        hbuf, w1t + (size_t)l * 4096 * 1024, nullptr, ffnb, b1 + l * DFF_,
        4096, 4096, 1024, 16);
    // FFN2, split-K=2 (128² dbuf kernel); fused combine(+b2) + next LN
    k_gemm<false, false, false, false, 2><<<2 * 8 * 32, 256, 0, stream>>>(
        ffnb, w2t + (size_t)l * 1024 * 4096, PpartF, nullptr, nullptr,
        1024, 4096, 2048, PSTRIDE);
    const float* ng = (l < L_ - 1) ? (ln1g + (l + 1) * D_) : lnfg;
    const float* nb = (l < L_ - 1) ? (ln1b + (l + 1) * D_) : lnfb;
    k_combine_ln<<<M_, 256, 0, stream>>>(
        x, PpartF, PSTRIDE, b2 + l * D_, ng, nb, hbuf);
  }

  // LM head: 8-phase 256², A-slab-pinned XCD map, full-line NT logit stores.
  k_gemm256<true, false, false, true><<<16 * 128, 512, 0, stream>>>(
      hbuf, lmwt, out, nullptr, lmb,
      V_, V_, 1024, 128);
}